// Round 6
// baseline (182035.010 us; speedup 1.0000x reference)
//
#include <hip/hip_runtime.h>
#include <hip/hip_bf16.h>

#define EPSN 1e-5f

typedef __hip_bfloat16 bf16;

__device__ __forceinline__ float b2f(bf16 v) { return __bfloat162float(v); }
__device__ __forceinline__ bf16 f2b(float v) { return __float2bfloat16(v); }
__device__ __forceinline__ void stv(bf16* p, size_t i, float v) { p[i] = f2b(v); }
__device__ __forceinline__ void stv(float* p, size_t i, float v) { p[i] = v; }

// ---------------- zero the stats scratch (atomicAdd target) -----------------
__global__ void zero_stats_kernel(float* __restrict__ stats) {
  int i = threadIdx.x;
  for (int k = i; k < 2048; k += 256) stats[k] = 0.f;
}

// ---------------- e1 pass 1: conv 3->64 7x7 p3 fused with stats (no store) --
__global__ __launch_bounds__(256) void conv_e1_stats_kernel(
    const float* __restrict__ x, const float* __restrict__ w,
    const float* __restrict__ bias, float* __restrict__ stats) {
  int co = blockIdx.y;  // 0..63
  int n = blockIdx.z;   // 0..3
  int pix = blockIdx.x * 256 + threadIdx.x;  // 0..262143
  int oh = pix >> 9, ow = pix & 511;
  float acc = bias[co];
  const float* xb = x + (size_t)n * 3 * 262144;
  const float* wb = w + co * 147;
  for (int ci = 0; ci < 3; ++ci) {
    const float* xc = xb + ci * 262144;
    const float* wc = wb + ci * 49;
    for (int kh = 0; kh < 7; ++kh) {
      int ih = oh - 3 + kh;
      if (ih < 0 || ih >= 512) continue;
      for (int kw = 0; kw < 7; ++kw) {
        int iw = ow - 3 + kw;
        if (iw < 0 || iw >= 512) continue;
        acc += xc[ih * 512 + iw] * wc[kh * 7 + kw];
      }
    }
  }
  __shared__ float ss[256], qq[256];
  ss[threadIdx.x] = acc;
  qq[threadIdx.x] = acc * acc;
  __syncthreads();
  for (int off = 128; off > 0; off >>= 1) {
    if (threadIdx.x < off) {
      ss[threadIdx.x] += ss[threadIdx.x + off];
      qq[threadIdx.x] += qq[threadIdx.x + off];
    }
    __syncthreads();
  }
  if (threadIdx.x == 0) {
    atomicAdd(&stats[n * 64 + co], ss[0]);
    atomicAdd(&stats[1024 + n * 64 + co], qq[0]);
  }
}

// ---------------- e1 pass 2: recompute conv + AdaLIN + relu -> fp32 (1 batch)
__global__ __launch_bounds__(256) void conv_e1_norm_kernel(
    const float* __restrict__ x, const float* __restrict__ w,
    const float* __restrict__ bias, const float* __restrict__ stats,
    float* __restrict__ y, int n) {
  int co = blockIdx.y;  // 0..63
  int pix = blockIdx.x * 256 + threadIdx.x;
  int oh = pix >> 9, ow = pix & 511;
  float acc = bias[co];
  const float* wb = w + co * 147;
  for (int ci = 0; ci < 3; ++ci) {
    const float* xc = x + ci * 262144;
    const float* wc = wb + ci * 49;
    for (int kh = 0; kh < 7; ++kh) {
      int ih = oh - 3 + kh;
      if (ih < 0 || ih >= 512) continue;
      for (int kw = 0; kw < 7; ++kw) {
        int iw = ow - 3 + kw;
        if (iw < 0 || iw >= 512) continue;
        acc += xc[ih * 512 + iw] * wc[kh * 7 + kw];
      }
    }
  }
  float sc = stats[2048 + n * 64 + co];
  float sh = stats[3072 + n * 64 + co];
  y[(size_t)co * 262144 + pix] = fmaxf(acc * sc + sh, 0.f);
}

// ---------------- generic direct conv (NCHW, OIHW fp32 weights) -------------
template <int ACT, typename Tin, typename Tout>
__global__ __launch_bounds__(256) void conv2d_kernel(
    const Tin* __restrict__ x, const float* __restrict__ w,
    const float* __restrict__ bias, Tout* __restrict__ y,
    int Ci, int Hi, int Wi, int Ho, int Wo, int K, int stride, int pad) {
  int co = blockIdx.y;
  int n = blockIdx.z;
  int Co = gridDim.y;
  int pix = blockIdx.x * 256 + threadIdx.x;
  if (pix >= Ho * Wo) return;
  int oh = pix / Wo, ow = pix % Wo;
  float acc = bias[co];
  const Tin* xb = x + (size_t)n * Ci * Hi * Wi;
  const float* wb = w + (size_t)co * Ci * K * K;
  for (int ci = 0; ci < Ci; ++ci) {
    const Tin* xc = xb + (size_t)ci * Hi * Wi;
    const float* wc = wb + (size_t)ci * K * K;
    for (int kh = 0; kh < K; ++kh) {
      int ih = oh * stride - pad + kh;
      if (ih < 0 || ih >= Hi) continue;
      const Tin* xr = xc + (size_t)ih * Wi;
      const float* wr = wc + kh * K;
      for (int kw = 0; kw < K; ++kw) {
        int iw = ow * stride - pad + kw;
        if (iw < 0 || iw >= Wi) continue;
        acc += (float)xr[iw] * wr[kw];
      }
    }
  }
  if (ACT == 1) acc = tanhf(acc);
  stv(y, ((size_t)(n * Co + co) * Ho + oh) * Wo + ow, acc);
}

// ---------------- specialized 3x3 s1 p1 conv, Ci=256, H=W=128, fp32 ---------
__global__ __launch_bounds__(256) void conv3x3_res_kernel(
    const float* __restrict__ x, const float* __restrict__ w,
    const float* __restrict__ bias, float* __restrict__ y) {
  int co = blockIdx.y;                       // 0..255
  int n = blockIdx.z;                        // 0..3
  int pix = blockIdx.x * 256 + threadIdx.x;  // 0..16383
  int oh = pix >> 7, ow = pix & 127;
  float acc = bias[co];
  const float* xb = x + (size_t)n * 256 * 16384;
  const float* wb = w + (size_t)co * 2304;
  if (oh > 0 && oh < 127 && ow > 0 && ow < 127) {
    const float* xp = xb + (oh - 1) * 128 + (ow - 1);
    for (int ci = 0; ci < 256; ++ci) {
      const float* wc = wb + ci * 9;
      const float* r0 = xp + (size_t)ci * 16384;
      acc += r0[0] * wc[0] + r0[1] * wc[1] + r0[2] * wc[2] +
             r0[128] * wc[3] + r0[129] * wc[4] + r0[130] * wc[5] +
             r0[256] * wc[6] + r0[257] * wc[7] + r0[258] * wc[8];
    }
  } else {
    for (int ci = 0; ci < 256; ++ci) {
      const float* xc = xb + (size_t)ci * 16384;
      const float* wc = wb + ci * 9;
      for (int kh = 0; kh < 3; ++kh) {
        int ih = oh - 1 + kh;
        if (ih < 0 || ih >= 128) continue;
        for (int kw = 0; kw < 3; ++kw) {
          int iw = ow - 1 + kw;
          if (iw < 0 || iw >= 128) continue;
          acc += xc[ih * 128 + iw] * wc[kh * 3 + kw];
        }
      }
    }
  }
  y[((size_t)(n * 256 + co) * 16384) + pix] = acc;
}

// ---------------- ConvTranspose2d k=3 s=2 p=1 outpad=1 (fp32 w [Ci,Co,3,3]) -
template <typename Tin, typename Tout>
__global__ __launch_bounds__(256) void convt2d_kernel(
    const Tin* __restrict__ x, const float* __restrict__ w,
    const float* __restrict__ bias, Tout* __restrict__ y,
    int Ci, int Hi, int Wi, int Ho, int Wo) {
  int co = blockIdx.y;
  int n = blockIdx.z;
  int Co = gridDim.y;
  int pix = blockIdx.x * 256 + threadIdx.x;
  if (pix >= Ho * Wo) return;
  int oh = pix / Wo, ow = pix % Wo;
  float acc = bias[co];
  const Tin* xb = x + (size_t)n * Ci * Hi * Wi;
  for (int ci = 0; ci < Ci; ++ci) {
    const Tin* xc = xb + (size_t)ci * Hi * Wi;
    const float* wc = w + ((size_t)ci * Co + co) * 9;
    for (int kh = 0; kh < 3; ++kh) {
      int t = oh + 1 - kh;
      if (t & 1) continue;
      int ih = t >> 1;
      if (ih < 0 || ih >= Hi) continue;
      for (int kw = 0; kw < 3; ++kw) {
        int u = ow + 1 - kw;
        if (u & 1) continue;
        int iw = u >> 1;
        if (iw < 0 || iw >= Wi) continue;
        acc += (float)xc[(size_t)ih * Wi + iw] * wc[kh * 3 + kw];
      }
    }
  }
  stv(y, ((size_t)(n * Co + co) * Ho + oh) * Wo + ow, acc);
}

// ---------------- per-(n,c) sum / sumsq reduction ---------------------------
template <typename Tin>
__global__ __launch_bounds__(256) void reduce_nc_kernel(
    const Tin* __restrict__ x, float* __restrict__ stats, int HW) {
  int b = blockIdx.x;
  const Tin* p = x + (size_t)b * HW;
  float s = 0.f, q = 0.f;
  for (int i = threadIdx.x; i < HW; i += 256) {
    float v = (float)p[i];
    s += v;
    q += v * v;
  }
  __shared__ float ss[256], qq[256];
  ss[threadIdx.x] = s;
  qq[threadIdx.x] = q;
  __syncthreads();
  for (int off = 128; off > 0; off >>= 1) {
    if (threadIdx.x < off) {
      ss[threadIdx.x] += ss[threadIdx.x + off];
      qq[threadIdx.x] += qq[threadIdx.x + off];
    }
    __syncthreads();
  }
  if (threadIdx.x == 0) {
    stats[b] = ss[0];
    stats[1024 + b] = qq[0];
  }
}

// ---------------- AdaLIN coefficients ---------------------------------------
__global__ void adalin_coef_kernel(float* __restrict__ stats,
                                   const float* __restrict__ rho,
                                   const float* __restrict__ gam,
                                   const float* __restrict__ bet, int N, int C,
                                   float invHW) {
  int i = blockIdx.x * blockDim.x + threadIdx.x;
  if (i >= N * C) return;
  int c = i % C;
  const float* sums = stats;
  const float* sqs = stats + 1024;
  float im = sums[i] * invHW;
  float iv = sqs[i] * invHW - im * im;
  float lsum = 0.f, lsq = 0.f;
  for (int n = 0; n < N; ++n) {
    lsum += sums[n * C + c];
    lsq += sqs[n * C + c];
  }
  float lm = lsum * invHW / N;
  float lv = lsq * invHW / N - lm * lm;
  float r = rho[c];
  float mean = r * im + (1.f - r) * lm;
  float var = fmaxf(r * iv + (1.f - r) * lv, 0.f);
  float sc = gam[c] / sqrtf(var + EPSN);
  stats[2048 + i] = sc;
  stats[3072 + i] = bet[c] - mean * sc;
}

// ---------------- InstanceNorm coefficients ---------------------------------
__global__ void inorm_coef_kernel(float* __restrict__ stats, int NC,
                                  float invHW) {
  int i = blockIdx.x * blockDim.x + threadIdx.x;
  if (i >= NC) return;
  float im = stats[i] * invHW;
  float iv = fmaxf(stats[1024 + i] * invHW - im * im, 0.f);
  float sc = 1.f / sqrtf(iv + EPSN);
  stats[2048 + i] = sc;
  stats[3072 + i] = -im * sc;
}

// ---------------- x = (relu?)(x*scale[nc] + shift[nc])  (in-place) ----------
template <typename T>
__global__ __launch_bounds__(256) void scale_shift_kernel(
    T* __restrict__ x, const float* __restrict__ stats, int HW, size_t total,
    int relu) {
  size_t i = (size_t)blockIdx.x * 256 + threadIdx.x;
  if (i >= total) return;
  int nc = (int)(i / (size_t)HW);
  float v = (float)x[i] * stats[2048 + nc] + stats[3072 + nc];
  if (relu) v = fmaxf(v, 0.f);
  stv(x, i, v);
}

// ---------------- dst = relu(dst + a)  (fp32) -------------------------------
__global__ __launch_bounds__(256) void add_relu_kernel(float* __restrict__ dst,
                                                       const float* __restrict__ a,
                                                       size_t total) {
  size_t i = (size_t)blockIdx.x * 256 + threadIdx.x;
  if (i >= total) return;
  dst[i] = fmaxf(dst[i] + a[i], 0.f);
}

// ---------------- windowed attention (all fp32) -----------------------------
// f,g: [B,32,128,128]; h: [B,256,128,128]; out: [B,256,128,128] fp32
__global__ __launch_bounds__(256) void win_attn_kernel(
    const float* __restrict__ f, const float* __restrict__ g,
    const float* __restrict__ h, float* __restrict__ out) {
  const int H = 128;
  int j = blockIdx.x;  // 0..31
  int i = blockIdx.y;  // 0..31
  int b = blockIdx.z;  // 0..3
  __shared__ float fs[32 * 64];
  __shared__ float gs[32 * 64];
  __shared__ float att[16 * 64];
  int t = threadIdx.x;
  for (int idx = t; idx < 32 * 64; idx += 256) {
    int c = idx >> 6, k = idx & 63;
    int hr = i * 4 + (k >> 3), wc = j * 4 + (k & 7);
    float fv = 0.f, gv = 0.f;
    if (hr < H && wc < H) {
      size_t o = ((size_t)(b * 32 + c) * H + hr) * H + wc;
      fv = f[o];
      gv = g[o];
    }
    fs[idx] = fv;
    gs[idx] = gv;
  }
  __syncthreads();
  for (int idx = t; idx < 1024; idx += 256) {
    int q = idx >> 6, k = idx & 63;
    int qi = (q >> 2) * 8 + (q & 3);  // window-flat index of query
    int hr = i * 4 + (k >> 3), wc = j * 4 + (k & 7);
    float s;
    if (hr < H && wc < H) {
      s = 0.f;
      for (int c = 0; c < 32; ++c) s += fs[c * 64 + qi] * gs[c * 64 + k];
    } else {
      s = -1e30f;
    }
    att[idx] = s;
  }
  __syncthreads();
  if (t < 16) {
    float m = -1e30f;
    for (int k = 0; k < 64; ++k) m = fmaxf(m, att[t * 64 + k]);
    float d = 0.f;
    for (int k = 0; k < 64; ++k) {
      float e = expf(att[t * 64 + k] - m);
      att[t * 64 + k] = e;
      d += e;
    }
    float inv = 1.f / d;
    for (int k = 0; k < 64; ++k) att[t * 64 + k] *= inv;
  }
  __syncthreads();
  int c = t;  // 0..255 output channel
  float accs[16];
  for (int q = 0; q < 16; ++q) accs[q] = 0.f;
  const float* hb = h + (size_t)(b * 256 + c) * H * H;
  for (int k = 0; k < 64; ++k) {
    int hr = i * 4 + (k >> 3), wc = j * 4 + (k & 7);
    if (hr >= H || wc >= H) continue;  // att weight is 0 there anyway
    float hv = hb[hr * H + wc];
    for (int q = 0; q < 16; ++q) accs[q] += hv * att[q * 64 + k];
  }
  for (int q = 0; q < 16; ++q) {
    int oh = i * 4 + (q >> 2), ow = j * 4 + (q & 3);
    out[((size_t)(b * 256 + c) * H + oh) * H + ow] = accs[q];
  }
}

// ============================================================================
extern "C" void kernel_launch(void* const* d_in, const int* in_sizes, int n_in,
                              void* d_out, int out_size, void* d_ws,
                              size_t ws_size, hipStream_t stream) {
  // fp32 inputs, fp32 outputs (reference dtypes).
  const float* x = (const float*)d_in[0];
  const float* w_e1 = (const float*)d_in[1];
  const float* b_e1 = (const float*)d_in[2];
  const float* rho1 = (const float*)d_in[3];
  const float* gam1 = (const float*)d_in[4];
  const float* bet1 = (const float*)d_in[5];
  const float* w_e2 = (const float*)d_in[6];
  const float* b_e2 = (const float*)d_in[7];
  const float* rho2 = (const float*)d_in[8];
  const float* gam2 = (const float*)d_in[9];
  const float* bet2 = (const float*)d_in[10];
  const float* w_e3 = (const float*)d_in[11];
  const float* b_e3 = (const float*)d_in[12];
  const float* rho3 = (const float*)d_in[13];
  const float* gam3 = (const float*)d_in[14];
  const float* bet3 = (const float*)d_in[15];
  const float* rw1 = (const float*)d_in[16];
  const float* rb1 = (const float*)d_in[17];
  const float* rw2 = (const float*)d_in[18];
  const float* rb2 = (const float*)d_in[19];
  const float* w_f = (const float*)d_in[20];
  const float* b_f = (const float*)d_in[21];
  const float* w_g = (const float*)d_in[22];
  const float* b_g = (const float*)d_in[23];
  const float* w_h = (const float*)d_in[24];
  const float* b_h = (const float*)d_in[25];
  const float* w_d1 = (const float*)d_in[26];
  const float* b_d1 = (const float*)d_in[27];
  const float* rho4 = (const float*)d_in[28];
  const float* gam4 = (const float*)d_in[29];
  const float* bet4 = (const float*)d_in[30];
  const float* w_d2 = (const float*)d_in[31];
  const float* b_d2 = (const float*)d_in[32];
  const float* rho5 = (const float*)d_in[33];
  const float* gam5 = (const float*)d_in[34];
  const float* bet5 = (const float*)d_in[35];
  const float* w_d3 = (const float*)d_in[36];
  const float* b_d3 = (const float*)d_in[37];

  // ---- ws layout (exactly 192 MiB). fp32 encoder/res/attn; bf16 decoder. ---
  // [0,  64 MiB): A64 (e1-normed, 1 batch) -> Cc (res state fp32)
  // [64, 192 MiB): Bb fp32 (e2 out) -> D[64,128)+E[128,192) fp32 ->
  //                f[64,72)+g[72,80) fp32, h->E -> d1out bf16 [128,192)
  // d2 out bf16 at [0,128).
  char* wsb = (char*)d_ws;
  float* A64 = (float*)wsb;                     // 16,777,216 f
  float* Cc = (float*)wsb;                      // 16,777,216 f
  float* Bb = (float*)(wsb + 67108864);         // 33,554,432 f
  float* D = (float*)(wsb + 67108864);          // 16,777,216 f
  float* E = (float*)(wsb + 134217728);         // 16,777,216 f
  float* F1 = (float*)(wsb + 67108864);         //  2,097,152 f
  float* F2 = (float*)(wsb + 75497472);         //  2,097,152 f
  bf16* Bb2 = (bf16*)(wsb + 134217728);         // 33,554,432 bf16 (d1 out)
  bf16* A2 = (bf16*)wsb;                        // 67,108,864 bf16 (d2 out)

  float* out_img = (float*)d_out;               // 3,145,728 f
  float* out_attn = out_img + 3145728;          // 16,777,216 f
  // 16 KiB stats scratch at head of d_out's img region; all uses precede the
  // head conv, which fully overwrites img. attn region never overlaps.
  float* stats = (float*)d_out;

  dim3 blk(256);

  // ---- encoder stage 1 (two-pass, fp32, no 256-MiB buffer needed) ----
  zero_stats_kernel<<<1, 256, 0, stream>>>(stats);
  conv_e1_stats_kernel<<<dim3(1024, 64, 4), blk, 0, stream>>>(x, w_e1, b_e1,
                                                              stats);
  adalin_coef_kernel<<<1, 256, 0, stream>>>(stats, rho1, gam1, bet1, 4, 64,
                                            1.f / 262144.f);
  for (int n = 0; n < 4; ++n) {
    conv_e1_norm_kernel<<<dim3(1024, 64), blk, 0, stream>>>(
        x + (size_t)n * 3 * 262144, w_e1, b_e1, stats, A64, n);
    // e2: conv 64->128 3x3 s2 p1 on this batch -> Bb slice (fp32)
    conv2d_kernel<0, float, float><<<dim3(256, 128, 1), blk, 0, stream>>>(
        A64, w_e2, b_e2, Bb + (size_t)n * 128 * 65536, 64, 512, 512, 256, 256,
        3, 2, 1);
  }
  // ---- e2 AdaLIN + relu (fp32 Bb) ----
  reduce_nc_kernel<float><<<512, blk, 0, stream>>>(Bb, stats, 65536);
  adalin_coef_kernel<<<2, 256, 0, stream>>>(stats, rho2, gam2, bet2, 4, 128,
                                            1.f / 65536.f);
  scale_shift_kernel<float><<<131072, blk, 0, stream>>>(Bb, stats, 65536,
                                                        (size_t)33554432, 1);
  // ---- encoder stage 3: conv 128->256 3x3 s2 p1, AdaLIN, relu (fp32) ----
  conv2d_kernel<0, float, float><<<dim3(64, 256, 4), blk, 0, stream>>>(
      Bb, w_e3, b_e3, Cc, 128, 256, 256, 128, 128, 3, 2, 1);
  reduce_nc_kernel<float><<<1024, blk, 0, stream>>>(Cc, stats, 16384);
  adalin_coef_kernel<<<4, 256, 0, stream>>>(stats, rho3, gam3, bet3, 4, 256,
                                            1.f / 16384.f);
  scale_shift_kernel<float><<<65536, blk, 0, stream>>>(Cc, stats, 16384,
                                                       (size_t)16777216, 1);
  // ---- 4 residual blocks (fp32) ----
  for (int r = 0; r < 4; ++r) {
    const float* rw1p = rw1 + (size_t)r * 256 * 256 * 9;
    const float* rb1p = rb1 + (size_t)r * 256;
    const float* rw2p = rw2 + (size_t)r * 256 * 256 * 9;
    const float* rb2p = rb2 + (size_t)r * 256;
    conv3x3_res_kernel<<<dim3(64, 256, 4), blk, 0, stream>>>(Cc, rw1p, rb1p, D);
    reduce_nc_kernel<float><<<1024, blk, 0, stream>>>(D, stats, 16384);
    inorm_coef_kernel<<<4, 256, 0, stream>>>(stats, 1024, 1.f / 16384.f);
    scale_shift_kernel<float><<<65536, blk, 0, stream>>>(D, stats, 16384,
                                                         (size_t)16777216, 1);
    conv3x3_res_kernel<<<dim3(64, 256, 4), blk, 0, stream>>>(D, rw2p, rb2p, E);
    reduce_nc_kernel<float><<<1024, blk, 0, stream>>>(E, stats, 16384);
    inorm_coef_kernel<<<4, 256, 0, stream>>>(stats, 1024, 1.f / 16384.f);
    scale_shift_kernel<float><<<65536, blk, 0, stream>>>(E, stats, 16384,
                                                         (size_t)16777216, 0);
    add_relu_kernel<<<65536, blk, 0, stream>>>(Cc, E, (size_t)16777216);
  }
  // ---- windowed attention (fp32 throughout; D dead -> f,g; E <- h) ----
  conv2d_kernel<0, float, float><<<dim3(64, 32, 4), blk, 0, stream>>>(
      Cc, w_f, b_f, F1, 256, 128, 128, 128, 128, 1, 1, 0);
  conv2d_kernel<0, float, float><<<dim3(64, 32, 4), blk, 0, stream>>>(
      Cc, w_g, b_g, F2, 256, 128, 128, 128, 128, 1, 1, 0);
  conv2d_kernel<0, float, float><<<dim3(64, 256, 4), blk, 0, stream>>>(
      Cc, w_h, b_h, E, 256, 128, 128, 128, 128, 1, 1, 0);
  win_attn_kernel<<<dim3(32, 32, 4), blk, 0, stream>>>(F1, F2, E, out_attn);
  // ---- decoder stage 1: convT 256->128, AdaLIN, relu (bf16 out) ----
  convt2d_kernel<float, bf16><<<dim3(256, 128, 4), blk, 0, stream>>>(
      Cc, w_d1, b_d1, Bb2, 256, 128, 128, 256, 256);
  reduce_nc_kernel<bf16><<<512, blk, 0, stream>>>(Bb2, stats, 65536);
  adalin_coef_kernel<<<2, 256, 0, stream>>>(stats, rho4, gam4, bet4, 4, 128,
                                            1.f / 65536.f);
  scale_shift_kernel<bf16><<<131072, blk, 0, stream>>>(Bb2, stats, 65536,
                                                       (size_t)33554432, 1);
  // ---- decoder stage 2: convT 128->64, AdaLIN, relu (bf16) ----
  convt2d_kernel<bf16, bf16><<<dim3(1024, 64, 4), blk, 0, stream>>>(
      Bb2, w_d2, b_d2, A2, 128, 256, 256, 512, 512);
  reduce_nc_kernel<bf16><<<256, blk, 0, stream>>>(A2, stats, 262144);
  adalin_coef_kernel<<<1, 256, 0, stream>>>(stats, rho5, gam5, bet5, 4, 64,
                                            1.f / 262144.f);
  scale_shift_kernel<bf16><<<262144, blk, 0, stream>>>(A2, stats, 262144,
                                                       (size_t)67108864, 1);
  // ---- head: conv 64->3 7x7 p3 + tanh -> fp32 img (overwrites stats) ----
  conv2d_kernel<1, bf16, float><<<dim3(1024, 3, 4), blk, 0, stream>>>(
      A2, w_d3, b_d3, out_img, 64, 512, 512, 512, 512, 7, 1, 3);
}

// Round 7
// 26382.620 us; speedup vs baseline: 6.8998x; 6.8998x over previous
//
#include <hip/hip_runtime.h>
#include <hip/hip_bf16.h>

#define EPSN 1e-5f

typedef __hip_bfloat16 bf16;

__device__ __forceinline__ float b2f(bf16 v) { return __bfloat162float(v); }
__device__ __forceinline__ bf16 f2b(float v) { return __float2bfloat16(v); }
__device__ __forceinline__ void stv(bf16* p, size_t i, float v) { p[i] = f2b(v); }
__device__ __forceinline__ void stv(float* p, size_t i, float v) { p[i] = v; }

// ---------------- zero the stats scratch (atomicAdd target) -----------------
__global__ void zero_stats_kernel(float* __restrict__ stats) {
  for (int k = threadIdx.x; k < 2048; k += 256) stats[k] = 0.f;
}

// ---------------- 7x7 conv p3, register-tiled: 4 px x CO_T co ---------------
// MODE 0: conv -> per-(n,co) sum/sumsq atomicAdd into stats (no activation out)
// MODE 1: conv -> AdaLIN scale/shift from stats + relu -> y (stored as n=0)
// MODE 2: conv -> tanh -> y (full n indexing)
template <int MODE, int CO_T, typename Tin>
__global__ __launch_bounds__(256) void conv7_tile(
    const Tin* __restrict__ x, const float* __restrict__ w,
    const float* __restrict__ bias, float* __restrict__ stats,
    float* __restrict__ y, int Ci, int H, int W, int n_ov) {
  __shared__ float ss[256], qq[256];
  int cog = blockIdx.y;
  int Co = gridDim.y * CO_T;
  int n = (MODE == 1) ? n_ov : blockIdx.z;
  int CG = W >> 2;
  int rpb = 256 / CG;
  int tid = threadIdx.x;
  int r = blockIdx.x * rpb + tid / CG;
  int c0 = (tid % CG) * 4;
  const Tin* xb = x + (size_t)n * Ci * H * W;
  int cr[7];
  float mr[7];
#pragma unroll
  for (int i = 0; i < 7; ++i) {
    int rr = r - 3 + i;
    mr[i] = (rr >= 0 && rr < H) ? 1.f : 0.f;
    cr[i] = min(max(rr, 0), H - 1);
  }
  int cc[10];
  float mc[10];
#pragma unroll
  for (int k = 0; k < 10; ++k) {
    int c = c0 - 3 + k;
    mc[k] = (c >= 0 && c < W) ? 1.f : 0.f;
    cc[k] = min(max(c, 0), W - 1);
  }
  float acc[CO_T][4];
#pragma unroll
  for (int j = 0; j < CO_T; ++j) {
    float b = bias[cog * CO_T + j];
#pragma unroll
    for (int p = 0; p < 4; ++p) acc[j][p] = b;
  }
  for (int ci = 0; ci < Ci; ++ci) {
    const Tin* xc = xb + (size_t)ci * H * W;
#pragma unroll
    for (int i = 0; i < 7; ++i) {
      const Tin* xr = xc + (size_t)cr[i] * W;
      float v[10];
#pragma unroll
      for (int k = 0; k < 10; ++k) v[k] = (float)xr[cc[k]] * (mr[i] * mc[k]);
#pragma unroll
      for (int j = 0; j < CO_T; ++j) {
        const float* wr =
            w + ((size_t)(cog * CO_T + j) * Ci + ci) * 49 + i * 7;
#pragma unroll
        for (int p = 0; p < 4; ++p) {
          acc[j][p] += v[p] * wr[0] + v[p + 1] * wr[1] + v[p + 2] * wr[2] +
                       v[p + 3] * wr[3] + v[p + 4] * wr[4] + v[p + 5] * wr[5] +
                       v[p + 6] * wr[6];
        }
      }
    }
  }
  if (MODE == 0) {
#pragma unroll
    for (int j = 0; j < CO_T; ++j) {
      float s = acc[j][0] + acc[j][1] + acc[j][2] + acc[j][3];
      float q = acc[j][0] * acc[j][0] + acc[j][1] * acc[j][1] +
                acc[j][2] * acc[j][2] + acc[j][3] * acc[j][3];
      ss[tid] = s;
      qq[tid] = q;
      __syncthreads();
      for (int off = 128; off > 0; off >>= 1) {
        if (tid < off) {
          ss[tid] += ss[tid + off];
          qq[tid] += qq[tid + off];
        }
        __syncthreads();
      }
      if (tid == 0) {
        atomicAdd(&stats[n * Co + cog * CO_T + j], ss[0]);
        atomicAdd(&stats[1024 + n * Co + cog * CO_T + j], qq[0]);
      }
      __syncthreads();
    }
  } else if (MODE == 1) {
#pragma unroll
    for (int j = 0; j < CO_T; ++j) {
      int co = cog * CO_T + j;
      float sc = stats[2048 + n * Co + co];
      float sh = stats[3072 + n * Co + co];
      float4 o;
      o.x = fmaxf(acc[j][0] * sc + sh, 0.f);
      o.y = fmaxf(acc[j][1] * sc + sh, 0.f);
      o.z = fmaxf(acc[j][2] * sc + sh, 0.f);
      o.w = fmaxf(acc[j][3] * sc + sh, 0.f);
      *(float4*)(y + ((size_t)co * H + r) * W + c0) = o;
    }
  } else {
#pragma unroll
    for (int j = 0; j < CO_T; ++j) {
      int co = cog * CO_T + j;
      float4 o;
      o.x = tanhf(acc[j][0]);
      o.y = tanhf(acc[j][1]);
      o.z = tanhf(acc[j][2]);
      o.w = tanhf(acc[j][3]);
      *(float4*)(y + ((size_t)(n * Co + co) * H + r) * W + c0) = o;
    }
  }
}

// ---------------- 3x3 s1 p1 conv, tiled 4 px x 4 co, fp32 -------------------
__global__ __launch_bounds__(256) void conv3x3s1_tile(
    const float* __restrict__ x, const float* __restrict__ w,
    const float* __restrict__ bias, float* __restrict__ y, int Ci, int H,
    int W) {
  int cog = blockIdx.y;
  int Co = gridDim.y * 4;
  int n = blockIdx.z;
  int CG = W >> 2;
  int rpb = 256 / CG;
  int tid = threadIdx.x;
  int r = blockIdx.x * rpb + tid / CG;
  int c0 = (tid % CG) * 4;
  const float* xb = x + (size_t)n * Ci * H * W;
  int cr[3];
  float mr[3];
#pragma unroll
  for (int i = 0; i < 3; ++i) {
    int rr = r - 1 + i;
    mr[i] = (rr >= 0 && rr < H) ? 1.f : 0.f;
    cr[i] = min(max(rr, 0), H - 1);
  }
  int ccl = max(c0 - 1, 0);
  float mcl = (c0 >= 1) ? 1.f : 0.f;
  int ccr = min(c0 + 4, W - 1);
  float mcr = (c0 + 4 < W) ? 1.f : 0.f;
  float acc[4][4];
#pragma unroll
  for (int j = 0; j < 4; ++j) {
    float b = bias[cog * 4 + j];
#pragma unroll
    for (int p = 0; p < 4; ++p) acc[j][p] = b;
  }
  for (int ci = 0; ci < Ci; ++ci) {
    const float* xc = xb + (size_t)ci * H * W;
    float v[3][6];
#pragma unroll
    for (int i = 0; i < 3; ++i) {
      const float* xr = xc + (size_t)cr[i] * W;
      float4 m = *(const float4*)(xr + c0);
      float mi = mr[i];
      v[i][0] = xr[ccl] * (mcl * mi);
      v[i][1] = m.x * mi;
      v[i][2] = m.y * mi;
      v[i][3] = m.z * mi;
      v[i][4] = m.w * mi;
      v[i][5] = xr[ccr] * (mcr * mi);
    }
#pragma unroll
    for (int j = 0; j < 4; ++j) {
      const float* wc = w + ((size_t)(cog * 4 + j) * Ci + ci) * 9;
#pragma unroll
      for (int p = 0; p < 4; ++p) {
        acc[j][p] += v[0][p] * wc[0] + v[0][p + 1] * wc[1] +
                     v[0][p + 2] * wc[2] + v[1][p] * wc[3] +
                     v[1][p + 1] * wc[4] + v[1][p + 2] * wc[5] +
                     v[2][p] * wc[6] + v[2][p + 1] * wc[7] +
                     v[2][p + 2] * wc[8];
      }
    }
  }
#pragma unroll
  for (int j = 0; j < 4; ++j) {
    float4 o = {acc[j][0], acc[j][1], acc[j][2], acc[j][3]};
    *(float4*)(y + ((size_t)(n * Co + cog * 4 + j) * H + r) * W + c0) = o;
  }
}

// ---------------- 3x3 s2 p1 conv, tiled 4 px x 4 co, fp32 -------------------
// launched with z=1 and pre-offset x/y (e2 per-batch) or z=4 (e3).
__global__ __launch_bounds__(256) void conv3x3s2_tile(
    const float* __restrict__ x, const float* __restrict__ w,
    const float* __restrict__ bias, float* __restrict__ y, int Ci, int Hi,
    int Wi) {
  int Ho = Hi >> 1, Wo = Wi >> 1;
  int cog = blockIdx.y;
  int Co = gridDim.y * 4;
  int n = blockIdx.z;
  int CG = Wo >> 2;
  int rpb = 256 / CG;
  int tid = threadIdx.x;
  int r = blockIdx.x * rpb + tid / CG;
  int c0 = (tid % CG) * 4;
  const float* xb = x + (size_t)n * Ci * Hi * Wi;
  int ir0 = 2 * r - 1;
  float mr0 = (ir0 >= 0) ? 1.f : 0.f;
  int cr0 = max(ir0, 0);
  int icl = 2 * c0 - 1;
  float mcl = (icl >= 0) ? 1.f : 0.f;
  int ccl = max(icl, 0);
  float acc[4][4];
#pragma unroll
  for (int j = 0; j < 4; ++j) {
    float b = bias[cog * 4 + j];
#pragma unroll
    for (int p = 0; p < 4; ++p) acc[j][p] = b;
  }
  for (int ci = 0; ci < Ci; ++ci) {
    const float* xc = xb + (size_t)ci * Hi * Wi;
    float v[3][9];
#pragma unroll
    for (int i = 0; i < 3; ++i) {
      int rr = (i == 0) ? cr0 : (2 * r - 1 + i);
      float mi = (i == 0) ? mr0 : 1.f;
      const float* xr = xc + (size_t)rr * Wi;
      float4 a = *(const float4*)(xr + 2 * c0);
      float4 b4 = *(const float4*)(xr + 2 * c0 + 4);
      v[i][0] = xr[ccl] * (mcl * mi);
      v[i][1] = a.x * mi;
      v[i][2] = a.y * mi;
      v[i][3] = a.z * mi;
      v[i][4] = a.w * mi;
      v[i][5] = b4.x * mi;
      v[i][6] = b4.y * mi;
      v[i][7] = b4.z * mi;
      v[i][8] = b4.w * mi;
    }
#pragma unroll
    for (int j = 0; j < 4; ++j) {
      const float* wc = w + ((size_t)(cog * 4 + j) * Ci + ci) * 9;
#pragma unroll
      for (int p = 0; p < 4; ++p) {
        acc[j][p] += v[0][2 * p] * wc[0] + v[0][2 * p + 1] * wc[1] +
                     v[0][2 * p + 2] * wc[2] + v[1][2 * p] * wc[3] +
                     v[1][2 * p + 1] * wc[4] + v[1][2 * p + 2] * wc[5] +
                     v[2][2 * p] * wc[6] + v[2][2 * p + 1] * wc[7] +
                     v[2][2 * p + 2] * wc[8];
      }
    }
  }
#pragma unroll
  for (int j = 0; j < 4; ++j) {
    float4 o = {acc[j][0], acc[j][1], acc[j][2], acc[j][3]};
    *(float4*)(y + ((size_t)(n * Co + cog * 4 + j) * Ho + r) * Wo + c0) = o;
  }
}

// ---------------- 1x1 conv, tiled 4 px x 4 co, fp32 -------------------------
__global__ __launch_bounds__(256) void conv1x1_tile(
    const float* __restrict__ x, const float* __restrict__ w,
    const float* __restrict__ bias, float* __restrict__ y, int Ci, int HW) {
  int cog = blockIdx.y;
  int Co = gridDim.y * 4;
  int n = blockIdx.z;
  int p0 = (blockIdx.x * 256 + threadIdx.x) * 4;
  const float* xb = x + (size_t)n * Ci * HW + p0;
  float acc[4][4];
#pragma unroll
  for (int j = 0; j < 4; ++j) {
    float b = bias[cog * 4 + j];
#pragma unroll
    for (int p = 0; p < 4; ++p) acc[j][p] = b;
  }
  for (int ci = 0; ci < Ci; ++ci) {
    float4 xv = *(const float4*)(xb + (size_t)ci * HW);
#pragma unroll
    for (int j = 0; j < 4; ++j) {
      float wv = w[(size_t)(cog * 4 + j) * Ci + ci];
      acc[j][0] += xv.x * wv;
      acc[j][1] += xv.y * wv;
      acc[j][2] += xv.z * wv;
      acc[j][3] += xv.w * wv;
    }
  }
#pragma unroll
  for (int j = 0; j < 4; ++j) {
    float4 o = {acc[j][0], acc[j][1], acc[j][2], acc[j][3]};
    *(float4*)(y + (size_t)(n * Co + cog * 4 + j) * HW + p0) = o;
  }
}

// ---------------- ConvTranspose2d k3 s2 p1 op1, tiled 2x2 quad x 4 co -------
// weights [Ci,Co,3,3]; output quad (2y,2x..2y+1,2x+1) from input patch (y,x)
template <typename Tin, typename Tout>
__global__ __launch_bounds__(256) void convt3x3_tile(
    const Tin* __restrict__ x, const float* __restrict__ w,
    const float* __restrict__ bias, Tout* __restrict__ y, int Ci, int Hi,
    int Wi) {
  int Ho = Hi * 2, Wo = Wi * 2;
  int cog = blockIdx.y;
  int Co = gridDim.y * 4;
  int n = blockIdx.z;
  int q = blockIdx.x * 256 + threadIdx.x;
  int yq = q / Wi, xq = q % Wi;
  const Tin* xb = x + (size_t)n * Ci * Hi * Wi;
  float mx = (xq + 1 < Wi) ? 1.f : 0.f;
  int x1 = min(xq + 1, Wi - 1);
  float my = (yq + 1 < Hi) ? 1.f : 0.f;
  int y1 = min(yq + 1, Hi - 1);
  float mxy = mx * my;
  float acc[4][4];
#pragma unroll
  for (int j = 0; j < 4; ++j) {
    float b = bias[cog * 4 + j];
#pragma unroll
    for (int p = 0; p < 4; ++p) acc[j][p] = b;
  }
  for (int ci = 0; ci < Ci; ++ci) {
    const Tin* xc = xb + (size_t)ci * Hi * Wi;
    float a = (float)xc[(size_t)yq * Wi + xq];
    float bv = (float)xc[(size_t)yq * Wi + x1] * mx;
    float c = (float)xc[(size_t)y1 * Wi + xq] * my;
    float d = (float)xc[(size_t)y1 * Wi + x1] * mxy;
#pragma unroll
    for (int j = 0; j < 4; ++j) {
      const float* wc = w + ((size_t)ci * Co + cog * 4 + j) * 9;
      acc[j][0] += a * wc[4];
      acc[j][1] += bv * wc[3] + a * wc[5];
      acc[j][2] += c * wc[1] + a * wc[7];
      acc[j][3] += d * wc[0] + c * wc[2] + bv * wc[6] + a * wc[8];
    }
  }
#pragma unroll
  for (int j = 0; j < 4; ++j) {
    size_t base = ((size_t)(n * Co + cog * 4 + j) * Ho + 2 * yq) * Wo + 2 * xq;
    stv(y, base, acc[j][0]);
    stv(y, base + 1, acc[j][1]);
    stv(y, base + Wo, acc[j][2]);
    stv(y, base + Wo + 1, acc[j][3]);
  }
}

// ---------------- per-(n,c) sum / sumsq reduction ---------------------------
template <typename Tin>
__global__ __launch_bounds__(256) void reduce_nc_kernel(
    const Tin* __restrict__ x, float* __restrict__ stats, int HW) {
  int b = blockIdx.x;
  const Tin* p = x + (size_t)b * HW;
  float s = 0.f, q = 0.f;
  for (int i = threadIdx.x; i < HW; i += 256) {
    float v = (float)p[i];
    s += v;
    q += v * v;
  }
  __shared__ float ss[256], qq[256];
  ss[threadIdx.x] = s;
  qq[threadIdx.x] = q;
  __syncthreads();
  for (int off = 128; off > 0; off >>= 1) {
    if (threadIdx.x < off) {
      ss[threadIdx.x] += ss[threadIdx.x + off];
      qq[threadIdx.x] += qq[threadIdx.x + off];
    }
    __syncthreads();
  }
  if (threadIdx.x == 0) {
    stats[b] = ss[0];
    stats[1024 + b] = qq[0];
  }
}

// ---------------- AdaLIN coefficients ---------------------------------------
__global__ void adalin_coef_kernel(float* __restrict__ stats,
                                   const float* __restrict__ rho,
                                   const float* __restrict__ gam,
                                   const float* __restrict__ bet, int N, int C,
                                   float invHW) {
  int i = blockIdx.x * blockDim.x + threadIdx.x;
  if (i >= N * C) return;
  int c = i % C;
  const float* sums = stats;
  const float* sqs = stats + 1024;
  float im = sums[i] * invHW;
  float iv = sqs[i] * invHW - im * im;
  float lsum = 0.f, lsq = 0.f;
  for (int n = 0; n < N; ++n) {
    lsum += sums[n * C + c];
    lsq += sqs[n * C + c];
  }
  float lm = lsum * invHW / N;
  float lv = lsq * invHW / N - lm * lm;
  float r = rho[c];
  float mean = r * im + (1.f - r) * lm;
  float var = fmaxf(r * iv + (1.f - r) * lv, 0.f);
  float sc = gam[c] / sqrtf(var + EPSN);
  stats[2048 + i] = sc;
  stats[3072 + i] = bet[c] - mean * sc;
}

// ---------------- InstanceNorm coefficients ---------------------------------
__global__ void inorm_coef_kernel(float* __restrict__ stats, int NC,
                                  float invHW) {
  int i = blockIdx.x * blockDim.x + threadIdx.x;
  if (i >= NC) return;
  float im = stats[i] * invHW;
  float iv = fmaxf(stats[1024 + i] * invHW - im * im, 0.f);
  float sc = 1.f / sqrtf(iv + EPSN);
  stats[2048 + i] = sc;
  stats[3072 + i] = -im * sc;
}

// ---------------- x = (relu?)(x*scale[nc] + shift[nc])  (in-place) ----------
template <typename T>
__global__ __launch_bounds__(256) void scale_shift_kernel(
    T* __restrict__ x, const float* __restrict__ stats, int HW, size_t total,
    int relu) {
  size_t i = (size_t)blockIdx.x * 256 + threadIdx.x;
  if (i >= total) return;
  int nc = (int)(i / (size_t)HW);
  float v = (float)x[i] * stats[2048 + nc] + stats[3072 + nc];
  if (relu) v = fmaxf(v, 0.f);
  stv(x, i, v);
}

// ---------------- dst = relu(dst + a)  (fp32) -------------------------------
__global__ __launch_bounds__(256) void add_relu_kernel(
    float* __restrict__ dst, const float* __restrict__ a, size_t total) {
  size_t i = (size_t)blockIdx.x * 256 + threadIdx.x;
  if (i >= total) return;
  dst[i] = fmaxf(dst[i] + a[i], 0.f);
}

// ---------------- windowed attention (all fp32) -----------------------------
__global__ __launch_bounds__(256) void win_attn_kernel(
    const float* __restrict__ f, const float* __restrict__ g,
    const float* __restrict__ h, float* __restrict__ out) {
  const int H = 128;
  int j = blockIdx.x;
  int i = blockIdx.y;
  int b = blockIdx.z;
  __shared__ float fs[32 * 64];
  __shared__ float gs[32 * 64];
  __shared__ float att[16 * 64];
  int t = threadIdx.x;
  for (int idx = t; idx < 32 * 64; idx += 256) {
    int c = idx >> 6, k = idx & 63;
    int hr = i * 4 + (k >> 3), wc = j * 4 + (k & 7);
    float fv = 0.f, gv = 0.f;
    if (hr < H && wc < H) {
      size_t o = ((size_t)(b * 32 + c) * H + hr) * H + wc;
      fv = f[o];
      gv = g[o];
    }
    fs[idx] = fv;
    gs[idx] = gv;
  }
  __syncthreads();
  for (int idx = t; idx < 1024; idx += 256) {
    int q = idx >> 6, k = idx & 63;
    int qi = (q >> 2) * 8 + (q & 3);
    int hr = i * 4 + (k >> 3), wc = j * 4 + (k & 7);
    float s;
    if (hr < H && wc < H) {
      s = 0.f;
      for (int c = 0; c < 32; ++c) s += fs[c * 64 + qi] * gs[c * 64 + k];
    } else {
      s = -1e30f;
    }
    att[idx] = s;
  }
  __syncthreads();
  if (t < 16) {
    float m = -1e30f;
    for (int k = 0; k < 64; ++k) m = fmaxf(m, att[t * 64 + k]);
    float d = 0.f;
    for (int k = 0; k < 64; ++k) {
      float e = expf(att[t * 64 + k] - m);
      att[t * 64 + k] = e;
      d += e;
    }
    float inv = 1.f / d;
    for (int k = 0; k < 64; ++k) att[t * 64 + k] *= inv;
  }
  __syncthreads();
  int c = t;
  float accs[16];
  for (int q = 0; q < 16; ++q) accs[q] = 0.f;
  const float* hb = h + (size_t)(b * 256 + c) * H * H;
  for (int k = 0; k < 64; ++k) {
    int hr = i * 4 + (k >> 3), wc = j * 4 + (k & 7);
    if (hr >= H || wc >= H) continue;
    float hv = hb[hr * H + wc];
    for (int q = 0; q < 16; ++q) accs[q] += hv * att[q * 64 + k];
  }
  for (int q = 0; q < 16; ++q) {
    int oh = i * 4 + (q >> 2), ow = j * 4 + (q & 3);
    out[((size_t)(b * 256 + c) * H + oh) * H + ow] = accs[q];
  }
}

// ============================================================================
extern "C" void kernel_launch(void* const* d_in, const int* in_sizes, int n_in,
                              void* d_out, int out_size, void* d_ws,
                              size_t ws_size, hipStream_t stream) {
  const float* x = (const float*)d_in[0];
  const float* w_e1 = (const float*)d_in[1];
  const float* b_e1 = (const float*)d_in[2];
  const float* rho1 = (const float*)d_in[3];
  const float* gam1 = (const float*)d_in[4];
  const float* bet1 = (const float*)d_in[5];
  const float* w_e2 = (const float*)d_in[6];
  const float* b_e2 = (const float*)d_in[7];
  const float* rho2 = (const float*)d_in[8];
  const float* gam2 = (const float*)d_in[9];
  const float* bet2 = (const float*)d_in[10];
  const float* w_e3 = (const float*)d_in[11];
  const float* b_e3 = (const float*)d_in[12];
  const float* rho3 = (const float*)d_in[13];
  const float* gam3 = (const float*)d_in[14];
  const float* bet3 = (const float*)d_in[15];
  const float* rw1 = (const float*)d_in[16];
  const float* rb1 = (const float*)d_in[17];
  const float* rw2 = (const float*)d_in[18];
  const float* rb2 = (const float*)d_in[19];
  const float* w_f = (const float*)d_in[20];
  const float* b_f = (const float*)d_in[21];
  const float* w_g = (const float*)d_in[22];
  const float* b_g = (const float*)d_in[23];
  const float* w_h = (const float*)d_in[24];
  const float* b_h = (const float*)d_in[25];
  const float* w_d1 = (const float*)d_in[26];
  const float* b_d1 = (const float*)d_in[27];
  const float* rho4 = (const float*)d_in[28];
  const float* gam4 = (const float*)d_in[29];
  const float* bet4 = (const float*)d_in[30];
  const float* w_d2 = (const float*)d_in[31];
  const float* b_d2 = (const float*)d_in[32];
  const float* rho5 = (const float*)d_in[33];
  const float* gam5 = (const float*)d_in[34];
  const float* bet5 = (const float*)d_in[35];
  const float* w_d3 = (const float*)d_in[36];
  const float* b_d3 = (const float*)d_in[37];

  // ws layout (192 MiB, validated round 6):
  // [0,64):   A64 (e1-norm batch) -> Cc fp32 -> A2 bf16 [0,128) (d2 out)
  // [64,192): Bb fp32 (e2) -> D[64,128)+E[128,192) fp32, F1/F2 in [64,80)
  //           -> Bb2 bf16 [128,192) (d1 out)
  char* wsb = (char*)d_ws;
  float* A64 = (float*)wsb;
  float* Cc = (float*)wsb;
  float* Bb = (float*)(wsb + 67108864);
  float* D = (float*)(wsb + 67108864);
  float* E = (float*)(wsb + 134217728);
  float* F1 = (float*)(wsb + 67108864);
  float* F2 = (float*)(wsb + 75497472);
  bf16* Bb2 = (bf16*)(wsb + 134217728);
  bf16* A2 = (bf16*)wsb;

  float* out_img = (float*)d_out;
  float* out_attn = out_img + 3145728;
  // 16 KiB stats scratch at head of img region; fully overwritten by head conv
  float* stats = (float*)d_out;

  dim3 blk(256);

  // ---- e1 pass 1: 7x7 conv + stats (no store) ----
  zero_stats_kernel<<<1, 256, 0, stream>>>(stats);
  conv7_tile<0, 4, float><<<dim3(256, 16, 4), blk, 0, stream>>>(
      x, w_e1, b_e1, stats, nullptr, 3, 512, 512, 0);
  adalin_coef_kernel<<<1, 256, 0, stream>>>(stats, rho1, gam1, bet1, 4, 64,
                                            1.f / 262144.f);
  // ---- e1 pass 2 (recompute+norm+relu, per batch) fused with e2 conv ----
  for (int n = 0; n < 4; ++n) {
    conv7_tile<1, 4, float><<<dim3(256, 16, 1), blk, 0, stream>>>(
        x, w_e1, b_e1, stats, A64, 3, 512, 512, n);
    conv3x3s2_tile<<<dim3(64, 32, 1), blk, 0, stream>>>(
        A64, w_e2, b_e2, Bb + (size_t)n * 128 * 65536, 64, 512, 512);
  }
  // ---- e2 AdaLIN + relu ----
  reduce_nc_kernel<float><<<512, blk, 0, stream>>>(Bb, stats, 65536);
  adalin_coef_kernel<<<2, 256, 0, stream>>>(stats, rho2, gam2, bet2, 4, 128,
                                            1.f / 65536.f);
  scale_shift_kernel<float><<<131072, blk, 0, stream>>>(Bb, stats, 65536,
                                                        (size_t)33554432, 1);
  // ---- e3: 3x3 s2, AdaLIN, relu ----
  conv3x3s2_tile<<<dim3(16, 64, 4), blk, 0, stream>>>(Bb, w_e3, b_e3, Cc, 128,
                                                      256, 256);
  reduce_nc_kernel<float><<<1024, blk, 0, stream>>>(Cc, stats, 16384);
  adalin_coef_kernel<<<4, 256, 0, stream>>>(stats, rho3, gam3, bet3, 4, 256,
                                            1.f / 16384.f);
  scale_shift_kernel<float><<<65536, blk, 0, stream>>>(Cc, stats, 16384,
                                                       (size_t)16777216, 1);
  // ---- 4 residual blocks ----
  for (int r = 0; r < 4; ++r) {
    const float* rw1p = rw1 + (size_t)r * 256 * 256 * 9;
    const float* rb1p = rb1 + (size_t)r * 256;
    const float* rw2p = rw2 + (size_t)r * 256 * 256 * 9;
    const float* rb2p = rb2 + (size_t)r * 256;
    conv3x3s1_tile<<<dim3(16, 64, 4), blk, 0, stream>>>(Cc, rw1p, rb1p, D, 256,
                                                        128, 128);
    reduce_nc_kernel<float><<<1024, blk, 0, stream>>>(D, stats, 16384);
    inorm_coef_kernel<<<4, 256, 0, stream>>>(stats, 1024, 1.f / 16384.f);
    scale_shift_kernel<float><<<65536, blk, 0, stream>>>(D, stats, 16384,
                                                         (size_t)16777216, 1);
    conv3x3s1_tile<<<dim3(16, 64, 4), blk, 0, stream>>>(D, rw2p, rb2p, E, 256,
                                                        128, 128);
    reduce_nc_kernel<float><<<1024, blk, 0, stream>>>(E, stats, 16384);
    inorm_coef_kernel<<<4, 256, 0, stream>>>(stats, 1024, 1.f / 16384.f);
    scale_shift_kernel<float><<<65536, blk, 0, stream>>>(E, stats, 16384,
                                                         (size_t)16777216, 0);
    add_relu_kernel<<<65536, blk, 0, stream>>>(Cc, E, (size_t)16777216);
  }
  // ---- attention: 1x1 convs f/g/h + windowed attention ----
  conv1x1_tile<<<dim3(16, 8, 4), blk, 0, stream>>>(Cc, w_f, b_f, F1, 256,
                                                   16384);
  conv1x1_tile<<<dim3(16, 8, 4), blk, 0, stream>>>(Cc, w_g, b_g, F2, 256,
                                                   16384);
  conv1x1_tile<<<dim3(16, 64, 4), blk, 0, stream>>>(Cc, w_h, b_h, E, 256,
                                                    16384);
  win_attn_kernel<<<dim3(32, 32, 4), blk, 0, stream>>>(F1, F2, E, out_attn);
  // ---- d1: convT 256->128, AdaLIN, relu (bf16 out) ----
  convt3x3_tile<float, bf16><<<dim3(64, 32, 4), blk, 0, stream>>>(
      Cc, w_d1, b_d1, Bb2, 256, 128, 128);
  reduce_nc_kernel<bf16><<<512, blk, 0, stream>>>(Bb2, stats, 65536);
  adalin_coef_kernel<<<2, 256, 0, stream>>>(stats, rho4, gam4, bet4, 4, 128,
                                            1.f / 65536.f);
  scale_shift_kernel<bf16><<<131072, blk, 0, stream>>>(Bb2, stats, 65536,
                                                       (size_t)33554432, 1);
  // ---- d2: convT 128->64, AdaLIN, relu (bf16) ----
  convt3x3_tile<bf16, bf16><<<dim3(256, 16, 4), blk, 0, stream>>>(
      Bb2, w_d2, b_d2, A2, 128, 256, 256);
  reduce_nc_kernel<bf16><<<256, blk, 0, stream>>>(A2, stats, 262144);
  adalin_coef_kernel<<<1, 256, 0, stream>>>(stats, rho5, gam5, bet5, 4, 64,
                                            1.f / 262144.f);
  scale_shift_kernel<bf16><<<262144, blk, 0, stream>>>(A2, stats, 262144,
                                                       (size_t)67108864, 1);
  // ---- head: 7x7 conv + tanh -> fp32 img (overwrites stats scratch) ----
  conv7_tile<2, 3, bf16><<<dim3(256, 1, 4), blk, 0, stream>>>(
      A2, w_d3, b_d3, stats, out_img, 64, 512, 512, 0);
}